// Round 11
// baseline (345.625 us; speedup 1.0000x reference)
//
#include <hip/hip_runtime.h>
#include <hip/hip_fp16.h>

#define HC 128
#define EPS_BN 1e-5f
#define NSTRIPE 8
#define AGG_BLOCKS 3072
#define BSHIFT 8                 // 256 nodes per bucket -> 391 buckets
#define BNODES (1 << BSHIFT)     // nodes per bucket (local index range)
#define NBKT 512                 // max bucket COUNT (histogram array size)
#define BCAP 6144                // bucket capacity (mean 4096 + 32 sigma)
#define CHUNK 4096               // edges per pass-1 block -> 391 blocks
#define EPT (CHUNK / 1024)
#define SRC_BITS 18              // src < 2^18

typedef _Float16 f16;
typedef f16  f16x8 __attribute__((ext_vector_type(8)));
typedef float f32x4 __attribute__((ext_vector_type(4)));

// ---------------- pass 1: LDS-staged bucket sort of each chunk --------------
__global__ __launch_bounds__(1024) void edge_bin(const int* __restrict__ src,
                                                 const int* __restrict__ dst,
                                                 int* __restrict__ gcur,
                                                 unsigned int* __restrict__ packed, int E) {
    __shared__ int cnt[NBKT];
    __shared__ int loc[NBKT];           // exclusive local offset of bucket run
    __shared__ int lcur[NBKT];          // local placement cursor
    __shared__ int gb[NBKT];            // global base - loc (writeout helper)
    __shared__ unsigned lbuf[CHUNK];    // bucket-ordered packed entries
    __shared__ unsigned short bkt16[CHUNK];
    __shared__ int totalSh;
    const int tid = threadIdx.x;
    const int e0 = blockIdx.x * CHUNK;
    int dreg[EPT];
    if (tid < NBKT) cnt[tid] = 0;
    __syncthreads();
#pragma unroll
    for (int i = 0; i < EPT; ++i) {
        int e = e0 + i * 1024 + tid;
        dreg[i] = (e < E) ? dst[e] : -1;
        if (dreg[i] >= 0) atomicAdd(&cnt[dreg[i] >> BSHIFT], 1);
    }
    __syncthreads();
    if (tid < NBKT) loc[tid] = cnt[tid];
    __syncthreads();
    for (int off = 1; off < NBKT; off <<= 1) {
        int t = 0;
        if (tid < NBKT && tid >= off) t = loc[tid - off];
        __syncthreads();
        if (tid < NBKT) loc[tid] += t;
        __syncthreads();
    }
    if (tid == NBKT - 1) totalSh = loc[tid];
    if (tid < NBKT) {
        int excl = loc[tid] - cnt[tid];
        loc[tid] = excl;
        lcur[tid] = excl;
        gb[tid] = tid * BCAP - excl +
                  ((cnt[tid] > 0) ? atomicAdd(&gcur[tid], cnt[tid]) : 0);
    }
    __syncthreads();
#pragma unroll
    for (int i = 0; i < EPT; ++i) {
        int e = e0 + i * 1024 + tid;
        if (dreg[i] >= 0) {
            int s = src[e];
            int b = dreg[i] >> BSHIFT;
            int pos = atomicAdd(&lcur[b], 1);
            lbuf[pos] = ((unsigned)(dreg[i] & (BNODES - 1)) << SRC_BITS) | (unsigned)s;
            bkt16[pos] = (unsigned short)b;
        }
    }
    __syncthreads();
    const int total = totalSh;
    for (int i = tid; i < total; i += 1024)
        packed[gb[bkt16[i]] + i] = lbuf[i];
}

// ---------------- pass 2: per-bucket degree+scan+placement, + wprep blocks --
__global__ __launch_bounds__(1024) void sort_wprep(const unsigned int* __restrict__ packed,
                                                   const int* __restrict__ gcur,
                                                   int2* __restrict__ rowptr2,
                                                   float* __restrict__ dis,
                                                   int* __restrict__ srcs, int n, int nbSort,
                                                   const float* __restrict__ W1,
                                                   const float* __restrict__ W2,
                                                   const float* __restrict__ Wm1,
                                                   f16* __restrict__ Wt1,
                                                   f16* __restrict__ Wt2,
                                                   f16* __restrict__ Wm1t) {
    if (blockIdx.x >= nbSort) {
        int idx = (blockIdx.x - nbSort) * 1024 + threadIdx.x;   // [0, 40960)
        if (idx < 16384) {
            int k = idx >> 7, c = idx & 127;
            Wt1[(size_t)c * HC + k] = (f16)W1[idx];
        } else if (idx < 32768) {
            int i = idx - 16384;
            int k = i >> 7, c = i & 127;
            Wt2[(size_t)c * HC + k] = (f16)W2[i];
        } else if (idx < 40960) {
            int i = idx - 32768;
            int c = i >> 7, k = i & 127;
            Wm1t[(size_t)c * HC + k] = (f16)Wm1[(size_t)k * 64 + c];
        }
        return;
    }
    __shared__ int cnt[BNODES];
    __shared__ int cur[BNODES];
    __shared__ int scn[BNODES];
    __shared__ int lbuf[BCAP];          // node-ordered src indices
    const int b = blockIdx.x;
    const int node0 = b << BSHIFT;
    const int tid = threadIdx.x;
    const int base = b * BCAP;
    const int count = gcur[b];          // gcur holds per-bucket count
    const int end  = base + count;

    if (tid < BNODES) cnt[tid] = 0;
    __syncthreads();
    for (int e = base + tid; e < end; e += 1024)
        atomicAdd(&cnt[packed[e] >> SRC_BITS], 1);
    __syncthreads();
    if (tid < BNODES) scn[tid] = cnt[tid];
    __syncthreads();
    for (int off = 1; off < BNODES; off <<= 1) {
        int t = 0;
        if (tid < BNODES && tid >= off) t = scn[tid - off];
        __syncthreads();
        if (tid < BNODES) scn[tid] += t;
        __syncthreads();
    }
    if (tid < BNODES) {
        int excl = scn[tid] - cnt[tid];
        int node = node0 + tid;
        if (node < n) {
            rowptr2[node] = make_int2(base + excl, base + excl + cnt[tid]);
            dis[node] = rsqrtf((float)cnt[tid] + 1.f);
        }
        cur[tid] = excl;
    }
    __syncthreads();
    for (int e = base + tid; e < end; e += 1024) {
        unsigned p = packed[e];
        int pos = atomicAdd(&cur[p >> SRC_BITS], 1);
        lbuf[pos] = (int)(p & ((1u << SRC_BITS) - 1));
    }
    __syncthreads();
    for (int i = tid; i < count; i += 1024)
        srcs[base + i] = lbuf[i];
}

// ---------------- MFMA GEMM: Y[row] = dis[row] * (T(X)[row] @ W) ------------
// 128 rows / 512 threads per block. B fragments read DIRECTLY from global Wt
// (32 KB, L1-resident after first touch) -> LDS/block ~36 KB -> 4 blocks/CU.
template<int SRC_F16, int TRANS>
__global__ __launch_bounds__(512) void gemm_mfma(const void* __restrict__ Xv,
                                                 const f16* __restrict__ Wt,
                                                 const float* __restrict__ stats,
                                                 const float* __restrict__ gamma,
                                                 const float* __restrict__ beta,
                                                 const float* __restrict__ dis,
                                                 f16* __restrict__ Y, int n) {
    __shared__ f16 Ah[128][136];
    __shared__ float sc[HC], sh[HC];
    const int tid  = threadIdx.x;
    const int row0 = blockIdx.x * 128;

    if constexpr (TRANS) {
        if (tid < 128) {
            float s = 0.f, q = 0.f;
#pragma unroll
            for (int t = 0; t < NSTRIPE; ++t) {
                s += stats[t * 256 + tid];
                q += stats[t * 256 + 128 + tid];
            }
            float m = s / (float)n;
            float v = q / (float)n - m * m;
            float scv = gamma[tid] * rsqrtf(fmaxf(v, 0.f) + EPS_BN);
            sc[tid] = scv;
            sh[tid] = beta[tid] - m * scv;
        }
    }

#pragma unroll
    for (int i = 0; i < 4; ++i) {
        int idx = i * 512 + tid;
        int r = idx >> 4, g = idx & 15;
        int grow = row0 + r;
        f16x8 h = {};
        if (grow < n) {
            if constexpr (SRC_F16) {
                f16x8 v = *(const f16x8*)((const f16*)Xv + (size_t)grow * HC + g * 8);
                if constexpr (TRANS) {
                    // sc/sh written above by this block's first 128 threads;
                    // need them visible before use
                } else h = v;
                if constexpr (TRANS) {
                    // defer BN apply until after barrier below
                    *(f16x8*)&Ah[r][g * 8] = v;
                    continue;
                }
            } else {
                const float* X = (const float*)Xv;
                float4 a = *(const float4*)(X + (size_t)grow * HC + g * 8);
                float4 c = *(const float4*)(X + (size_t)grow * HC + g * 8 + 4);
                h[0] = (f16)a.x; h[1] = (f16)a.y; h[2] = (f16)a.z; h[3] = (f16)a.w;
                h[4] = (f16)c.x; h[5] = (f16)c.y; h[6] = (f16)c.z; h[7] = (f16)c.w;
            }
        }
        *(f16x8*)&Ah[r][g * 8] = h;
    }
    __syncthreads();

    if constexpr (TRANS) {
        // apply BN+ReLU in-place in Ah (sc/sh now visible)
#pragma unroll
        for (int i = 0; i < 4; ++i) {
            int idx = i * 512 + tid;
            int r = idx >> 4, g = idx & 15;
            int grow = row0 + r;
            f16x8 v = *(const f16x8*)&Ah[r][g * 8];
            f16x8 h = {};
            if (grow < n) {
#pragma unroll
                for (int j = 0; j < 8; ++j) {
                    float f = (float)v[j];
                    f = fmaxf(fmaf(f, sc[g * 8 + j], sh[g * 8 + j]), 0.f);
                    h[j] = (f16)f;
                }
            }
            *(f16x8*)&Ah[r][g * 8] = h;
        }
        __syncthreads();
    }

    const int wv   = tid >> 6;          // 0..7, wave handles rows wv*16..+15
    const int lane = tid & 63;
    const int m    = lane & 15;
    const int kq   = (lane >> 4) * 8;

    f32x4 acc[8] = {};
#pragma unroll
    for (int kc = 0; kc < HC; kc += 32) {
        f16x8 a = *(const f16x8*)&Ah[wv * 16 + m][kc + kq];
#pragma unroll
        for (int t = 0; t < 8; ++t) {
            f16x8 b = *(const f16x8*)(Wt + (size_t)(t * 16 + m) * HC + kc + kq);
            acc[t] = __builtin_amdgcn_mfma_f32_16x16x32_f16(a, b, acc[t], 0, 0, 0);
        }
    }

    // epilogue: scale by dis, transpose through Ah, vector-store
    __syncthreads();
    {
        const int rg = (lane >> 4) * 4;
        float dv[4];
#pragma unroll
        for (int r = 0; r < 4; ++r) {
            int grow = row0 + wv * 16 + rg + r;
            dv[r] = (grow < n) ? dis[grow] : 0.f;
        }
#pragma unroll
        for (int t = 0; t < 8; ++t)
#pragma unroll
            for (int r = 0; r < 4; ++r)
                Ah[wv * 16 + rg + r][t * 16 + m] = (f16)(acc[t][r] * dv[r]);
    }
    __syncthreads();
#pragma unroll
    for (int i = 0; i < 4; ++i) {
        int idx = i * 512 + tid;
        int r = idx >> 4, g = idx & 15;
        int grow = row0 + r;
        if (grow < n)
            *(f16x8*)(Y + (size_t)grow * HC + g * 8) = *(const f16x8*)&Ah[r][g * 8];
    }
}

// ---------------- CSR gather agg, 4 gathers in flight (round-9 proven) ------
// xws[s] = dis[s]*xw[s]; out[v] = dis[v]*(sum_e xws[s] + xws[v]) + b.
__global__ __launch_bounds__(256) void gcn_agg_f16(const f16* __restrict__ xws,
                                                   const int* __restrict__ srcs,
                                                   const int2* __restrict__ rowptr2,
                                                   const float* __restrict__ dis,
                                                   const float* __restrict__ bias,
                                                   f16* __restrict__ out,
                                                   float* __restrict__ stats,
                                                   int n, int nwaves) {
    __shared__ float lds_s[4][128], lds_q[4][128];
    const int wv   = threadIdx.x >> 6;
    const int lane = threadIdx.x & 63;
    const int g    = lane >> 4;      // edge subgroup 0..3
    const int cg   = lane & 15;      // channel group (8 channels)

    float b8[8];
#pragma unroll
    for (int j = 0; j < 8; ++j) b8[j] = bias[cg * 8 + j];

    float s8[8] = {}, q8[8] = {};

    for (int node = blockIdx.x * 4 + wv; node < n; node += nwaves) {
        const int2 rp = rowptr2[node];
        const int e1 = rp.y;
        float acc[8] = {};
        int e  = rp.x;
        int i0 = e + g, i1 = i0 + 4, i2 = i0 + 8, i3 = i0 + 12;
        int s0 = (i0 < e1) ? srcs[i0] : n;   // n -> zero pad row
        int s1 = (i1 < e1) ? srcs[i1] : n;
        int s2 = (i2 < e1) ? srcs[i2] : n;
        int s3 = (i3 < e1) ? srcs[i3] : n;
        while (e < e1) {
            int en = e + 16;
            int j0 = en + g, j1 = j0 + 4, j2 = j0 + 8, j3 = j0 + 12;
            int t0 = (j0 < e1) ? srcs[j0] : n;   // prefetch next iter's indices
            int t1 = (j1 < e1) ? srcs[j1] : n;
            int t2 = (j2 < e1) ? srcs[j2] : n;
            int t3 = (j3 < e1) ? srcs[j3] : n;
            f16x8 v0 = *(const f16x8*)(xws + (size_t)s0 * HC + cg * 8);
            f16x8 v1 = *(const f16x8*)(xws + (size_t)s1 * HC + cg * 8);
            f16x8 v2 = *(const f16x8*)(xws + (size_t)s2 * HC + cg * 8);
            f16x8 v3 = *(const f16x8*)(xws + (size_t)s3 * HC + cg * 8);
            f16x8 p01 = v0 + v1;                 // v_pk_add_f16, zeros exact
            f16x8 p23 = v2 + v3;
#pragma unroll
            for (int j = 0; j < 8; ++j)
                acc[j] += (float)p01[j] + (float)p23[j];
            s0 = t0; s1 = t1; s2 = t2; s3 = t3; e = en;
        }
#pragma unroll
        for (int j = 0; j < 8; ++j) acc[j] += __shfl_xor(acc[j], 16);
#pragma unroll
        for (int j = 0; j < 8; ++j) acc[j] += __shfl_xor(acc[j], 32);

        if (g == 0) {
            float dv = dis[node];
            f16x8 self = *(const f16x8*)(xws + (size_t)node * HC + cg * 8);
            f16x8 o;
#pragma unroll
            for (int j = 0; j < 8; ++j) {
                float r = fmaf(acc[j] + (float)self[j], dv, b8[j]);
                o[j] = (f16)r;
                s8[j] += r;
                q8[j] += r * r;
            }
            *(f16x8*)(out + (size_t)node * HC + cg * 8) = o;
        }
    }

    if (g == 0) {
#pragma unroll
        for (int j = 0; j < 8; ++j) {
            lds_s[wv][cg * 8 + j] = s8[j];
            lds_q[wv][cg * 8 + j] = q8[j];
        }
    }
    __syncthreads();
    float* stripe = stats + (size_t)(blockIdx.x & (NSTRIPE - 1)) * 256;
    if (threadIdx.x < 128) {
        float s = lds_s[0][threadIdx.x] + lds_s[1][threadIdx.x] +
                  lds_s[2][threadIdx.x] + lds_s[3][threadIdx.x];
        float q = lds_q[0][threadIdx.x] + lds_q[1][threadIdx.x] +
                  lds_q[2][threadIdx.x] + lds_q[3][threadIdx.x];
        atomicAdd(&stripe[threadIdx.x], s);
        atomicAdd(&stripe[128 + threadIdx.x], q);
    }
}

// ---------------- MFMA MLP head (BN2 finalize + BN+ReLU + both layers) ------
__global__ __launch_bounds__(256) void mlp_mfma(const f16* __restrict__ h,
                                                const float* __restrict__ stats,
                                                const float* __restrict__ gamma,
                                                const float* __restrict__ beta,
                                                const f16* __restrict__ Wm1t,
                                                const float* __restrict__ bm1,
                                                const float* __restrict__ Wm2,
                                                const float* __restrict__ bm2,
                                                float* __restrict__ out, int n) {
    __shared__ f16 Hs[64][136];
    __shared__ f16 Ws[64][136];
    __shared__ float sc[HC], sh[HC], bmv[64], w2v[64];
    const int tid  = threadIdx.x;
    const int row0 = blockIdx.x * 64;

    if (tid < 128) {
        float s = 0.f, q = 0.f;
#pragma unroll
        for (int t = 0; t < NSTRIPE; ++t) {
            s += stats[t * 256 + tid];
            q += stats[t * 256 + 128 + tid];
        }
        float m = s / (float)n;
        float v = q / (float)n - m * m;
        float scv = gamma[tid] * rsqrtf(fmaxf(v, 0.f) + EPS_BN);
        sc[tid] = scv;
        sh[tid] = beta[tid] - m * scv;
    }
    if (tid < 64) { bmv[tid] = bm1[tid]; w2v[tid] = Wm2[tid]; }

#pragma unroll
    for (int i = 0; i < 4; ++i) {
        int idx = i * 256 + tid;
        int r = idx >> 4, g = idx & 15;
        *(f16x8*)&Ws[r][g * 8] = *(const f16x8*)(Wm1t + (size_t)r * HC + g * 8);
    }
    __syncthreads();

#pragma unroll
    for (int i = 0; i < 4; ++i) {
        int idx = i * 256 + tid;
        int r = idx >> 4, g = idx & 15;
        int grow = row0 + r;
        f16x8 hv = {};
        if (grow < n) {
            f16x8 v = *(const f16x8*)(h + (size_t)grow * HC + g * 8);
#pragma unroll
            for (int j = 0; j < 8; ++j) {
                float f = (float)v[j];
                f = fmaxf(fmaf(f, sc[g * 8 + j], sh[g * 8 + j]), 0.f);
                hv[j] = (f16)f;
            }
        }
        *(f16x8*)&Hs[r][g * 8] = hv;
    }
    __syncthreads();

    const int wv   = tid >> 6;
    const int lane = tid & 63;
    const int m    = lane & 15;
    const int kq   = (lane >> 4) * 8;

    f32x4 acc[4] = {};
#pragma unroll
    for (int kc = 0; kc < HC; kc += 32) {
        f16x8 a = *(const f16x8*)&Hs[wv * 16 + m][kc + kq];
#pragma unroll
        for (int t = 0; t < 4; ++t) {
            f16x8 b = *(const f16x8*)&Ws[t * 16 + m][kc + kq];
            acc[t] = __builtin_amdgcn_mfma_f32_16x16x32_f16(a, b, acc[t], 0, 0, 0);
        }
    }

    float part[4];
#pragma unroll
    for (int reg = 0; reg < 4; ++reg) {
        float s = 0.f;
#pragma unroll
        for (int t = 0; t < 4; ++t) {
            int col = t * 16 + m;
            s += fmaxf(acc[t][reg] + bmv[col], 0.f) * w2v[col];
        }
        part[reg] = s;
    }
#pragma unroll
    for (int off = 1; off < 16; off <<= 1) {
#pragma unroll
        for (int reg = 0; reg < 4; ++reg)
            part[reg] += __shfl_xor(part[reg], off);
    }
    if (m == 0) {
        int rbase = row0 + wv * 16 + (lane >> 4) * 4;
        float bb = bm2[0];
#pragma unroll
        for (int reg = 0; reg < 4; ++reg) {
            int row = rbase + reg;
            if (row < n) out[row] = part[reg] + bb;
        }
    }
}

extern "C" void kernel_launch(void* const* d_in, const int* in_sizes, int n_in,
                              void* d_out, int out_size, void* d_ws, size_t ws_size,
                              hipStream_t stream) {
    const float* x   = (const float*)d_in[0];
    const int*   ei  = (const int*)  d_in[1];
    const float* W1  = (const float*)d_in[2];
    const float* b1  = (const float*)d_in[3];
    const float* g1  = (const float*)d_in[4];
    const float* be1 = (const float*)d_in[5];
    const float* W2  = (const float*)d_in[6];
    const float* b2  = (const float*)d_in[7];
    const float* g2  = (const float*)d_in[8];
    const float* be2 = (const float*)d_in[9];
    const float* Wm1 = (const float*)d_in[10];
    const float* bm1 = (const float*)d_in[11];
    const float* Wm2 = (const float*)d_in[12];
    const float* bm2 = (const float*)d_in[13];
    float* out = (float*)d_out;

    const int n = in_sizes[0] / HC;       // 100000
    const int E = in_sizes[1] / 2;        // 1600000
    const int* srcp = ei;
    const int* dstp = ei + E;
    const int nb = (n + BNODES - 1) >> BSHIFT;   // 391 buckets

    char* ws = (char*)d_ws;
    size_t off = 0;
    auto alloc = [&](size_t bytes) { void* p = ws + off; off = (off + bytes + 511) & ~511ULL; return p; };
    // xws FIRST so that {pad row | gcur | stats} is one contiguous zero range
    f16*    xws     = (f16*)   alloc((size_t)(n + 1) * HC * 2);   // +1 zero pad row
    int*    gcur    = (int*)   alloc(NBKT * 4);
    float*  stats   = (float*) alloc(2 * NSTRIPE * 256 * 4);      // stats1 | stats2
    float*  stats1  = stats;
    float*  stats2  = stats + NSTRIPE * 256;
    float*  dis     = (float*) alloc((size_t)n * 4);
    int2*   rowptr2 = (int2*)  alloc((size_t)n * 8);
    unsigned int* packed = (unsigned int*)alloc((size_t)nb * BCAP * 4);
    int*    srcs    = (int*)   alloc((size_t)nb * BCAP * 4);
    f16*    bufBh   = (f16*)   alloc((size_t)n * HC * 2);
    f16*    Wt1     = (f16*)   alloc((size_t)HC * HC * 2);
    f16*    Wt2     = (f16*)   alloc((size_t)HC * HC * 2);
    f16*    Wm1t    = (f16*)   alloc((size_t)64 * HC * 2);

    const int gemmBlocks = (n + 127) / 128;       // 128-row blocks, 512 threads
    const int mlpBlocks  = (n + 63) / 64;
    const int binBlocks  = (E + CHUNK - 1) / CHUNK;   // 391
    const int wprepBlks  = 40;                    // 40960 / 1024
    const int aggWaves   = AGG_BLOCKS * 4;

    // ---- single memset: pad row + (alignment slack) + gcur + stats ----
    {
        char* z0 = (char*)(xws + (size_t)n * HC);
        size_t zlen = (size_t)((char*)(stats + 2 * NSTRIPE * 256) - z0);
        hipMemsetAsync(z0, 0, zlen, stream);
    }

    // ---- CSR build: bin -> per-bucket sort (+ weight prep riding along) ----
    edge_bin<<<binBlocks, 1024, 0, stream>>>(srcp, dstp, gcur, packed, E);
    sort_wprep<<<nb + wprepBlks, 1024, 0, stream>>>(packed, gcur, rowptr2, dis, srcs, n, nb,
                                                    W1, W2, Wm1, Wt1, Wt2, Wm1t);

    // ---- layer 1 ----
    gemm_mfma<0, 0><<<gemmBlocks, 512, 0, stream>>>(x, Wt1, nullptr, nullptr, nullptr,
                                                    dis, xws, n);
    gcn_agg_f16<<<AGG_BLOCKS, 256, 0, stream>>>(xws, srcs, rowptr2, dis, b1,
                                                bufBh, stats1, n, aggWaves);

    // ---- layer 2 (BN1 finalize + BN+ReLU fused into GEMM staging) ----
    gemm_mfma<1, 1><<<gemmBlocks, 512, 0, stream>>>(bufBh, Wt2, stats1, g1, be1,
                                                    dis, xws, n);
    gcn_agg_f16<<<AGG_BLOCKS, 256, 0, stream>>>(xws, srcs, rowptr2, dis, b2,
                                                bufBh, stats2, n, aggWaves);

    // ---- MLP head (BN2 finalize + BN+ReLU + both layers fused, MFMA) ----
    mlp_mfma<<<mlpBlocks, 256, 0, stream>>>(bufBh, stats2, g2, be2, Wm1t, bm1, Wm2, bm2,
                                            out, n);
}

// Round 12
// 298.553 us; speedup vs baseline: 1.1577x; 1.1577x over previous
//
#include <hip/hip_runtime.h>
#include <hip/hip_fp16.h>

#define HC 128
#define EPS_BN 1e-5f
#define NSTRIPE 8
#define AGG_BLOCKS 3072
#define BSHIFT 8                 // 256 nodes per bucket -> 391 buckets
#define BNODES (1 << BSHIFT)     // nodes per bucket (local index range)
#define NBKT 512                 // max bucket COUNT (histogram array size)
#define BCAP 6144                // bucket capacity (mean 4096 + 32 sigma)
#define CHUNK 4096               // edges per pass-1 block -> 391 blocks
#define EPT (CHUNK / 1024)
#define SRC_BITS 18              // src < 2^18

typedef _Float16 f16;
typedef f16  f16x8 __attribute__((ext_vector_type(8)));
typedef float f32x4 __attribute__((ext_vector_type(4)));

// ---------------- pass 1: LDS-staged bucket sort of each chunk --------------
// Edges are ordered by bucket in LDS, then written out as contiguous runs
// (coalesced) instead of per-edge scattered cursor writes.
__global__ __launch_bounds__(1024) void edge_bin(const int* __restrict__ src,
                                                 const int* __restrict__ dst,
                                                 int* __restrict__ gcur,
                                                 unsigned int* __restrict__ packed, int E) {
    __shared__ int cnt[NBKT];
    __shared__ int loc[NBKT];           // exclusive local offset of bucket run
    __shared__ int lcur[NBKT];          // local placement cursor
    __shared__ int gb[NBKT];            // global base - loc (writeout helper)
    __shared__ unsigned lbuf[CHUNK];    // bucket-ordered packed entries
    __shared__ unsigned short bkt16[CHUNK];
    __shared__ int totalSh;
    const int tid = threadIdx.x;
    const int e0 = blockIdx.x * CHUNK;
    int dreg[EPT];
    if (tid < NBKT) cnt[tid] = 0;
    __syncthreads();
#pragma unroll
    for (int i = 0; i < EPT; ++i) {
        int e = e0 + i * 1024 + tid;
        dreg[i] = (e < E) ? dst[e] : -1;
        if (dreg[i] >= 0) atomicAdd(&cnt[dreg[i] >> BSHIFT], 1);
    }
    __syncthreads();
    // inclusive scan over buckets -> loc (exclusive), lcur, gb
    if (tid < NBKT) loc[tid] = cnt[tid];
    __syncthreads();
    for (int off = 1; off < NBKT; off <<= 1) {
        int t = 0;
        if (tid < NBKT && tid >= off) t = loc[tid - off];
        __syncthreads();
        if (tid < NBKT) loc[tid] += t;
        __syncthreads();
    }
    if (tid == NBKT - 1) totalSh = loc[tid];
    if (tid < NBKT) {
        int excl = loc[tid] - cnt[tid];
        loc[tid] = excl;
        lcur[tid] = excl;
        gb[tid] = tid * BCAP - excl +
                  ((cnt[tid] > 0) ? atomicAdd(&gcur[tid], cnt[tid]) : 0);
    }
    __syncthreads();
    // place into LDS, bucket-ordered
#pragma unroll
    for (int i = 0; i < EPT; ++i) {
        int e = e0 + i * 1024 + tid;
        if (dreg[i] >= 0) {
            int s = src[e];
            int b = dreg[i] >> BSHIFT;
            int pos = atomicAdd(&lcur[b], 1);
            lbuf[pos] = ((unsigned)(dreg[i] & (BNODES - 1)) << SRC_BITS) | (unsigned)s;
            bkt16[pos] = (unsigned short)b;
        }
    }
    __syncthreads();
    // coalesced writeout of bucket runs
    const int total = totalSh;
    for (int i = tid; i < total; i += 1024)
        packed[gb[bkt16[i]] + i] = lbuf[i];
}

// ---------------- pass 2: per-bucket degree+scan+placement, + wprep blocks --
// srcs placement goes through LDS; global write is a coalesced stream.
__global__ __launch_bounds__(1024) void sort_wprep(const unsigned int* __restrict__ packed,
                                                   const int* __restrict__ gcur,
                                                   int2* __restrict__ rowptr2,
                                                   float* __restrict__ dis,
                                                   int* __restrict__ srcs, int n, int nbSort,
                                                   const float* __restrict__ W1,
                                                   const float* __restrict__ W2,
                                                   const float* __restrict__ Wm1,
                                                   f16* __restrict__ Wt1,
                                                   f16* __restrict__ Wt2,
                                                   f16* __restrict__ Wm1t) {
    if (blockIdx.x >= nbSort) {
        int idx = (blockIdx.x - nbSort) * 1024 + threadIdx.x;   // [0, 40960)
        if (idx < 16384) {
            int k = idx >> 7, c = idx & 127;
            Wt1[(size_t)c * HC + k] = (f16)W1[idx];
        } else if (idx < 32768) {
            int i = idx - 16384;
            int k = i >> 7, c = i & 127;
            Wt2[(size_t)c * HC + k] = (f16)W2[i];
        } else if (idx < 40960) {
            int i = idx - 32768;
            int c = i >> 7, k = i & 127;
            Wm1t[(size_t)c * HC + k] = (f16)Wm1[(size_t)k * 64 + c];
        }
        return;
    }
    __shared__ int cnt[BNODES];
    __shared__ int cur[BNODES];
    __shared__ int scn[BNODES];
    __shared__ int lbuf[BCAP];          // node-ordered src indices
    const int b = blockIdx.x;
    const int node0 = b << BSHIFT;
    const int tid = threadIdx.x;
    const int base = b * BCAP;
    const int count = gcur[b];          // gcur holds per-bucket count
    const int end  = base + count;

    if (tid < BNODES) cnt[tid] = 0;
    __syncthreads();
    for (int e = base + tid; e < end; e += 1024)
        atomicAdd(&cnt[packed[e] >> SRC_BITS], 1);
    __syncthreads();
    if (tid < BNODES) scn[tid] = cnt[tid];
    __syncthreads();
    for (int off = 1; off < BNODES; off <<= 1) {
        int t = 0;
        if (tid < BNODES && tid >= off) t = scn[tid - off];
        __syncthreads();
        if (tid < BNODES) scn[tid] += t;
        __syncthreads();
    }
    if (tid < BNODES) {
        int excl = scn[tid] - cnt[tid];
        int node = node0 + tid;
        if (node < n) {
            rowptr2[node] = make_int2(base + excl, base + excl + cnt[tid]);
            dis[node] = rsqrtf((float)cnt[tid] + 1.f);
        }
        cur[tid] = excl;
    }
    __syncthreads();
    // place into LDS (node-ordered), then stream out coalesced
    for (int e = base + tid; e < end; e += 1024) {
        unsigned p = packed[e];
        int pos = atomicAdd(&cur[p >> SRC_BITS], 1);
        lbuf[pos] = (int)(p & ((1u << SRC_BITS) - 1));
    }
    __syncthreads();
    for (int i = tid; i < count; i += 1024)
        srcs[base + i] = lbuf[i];
}

// ---------------- MFMA GEMM: Y[row] = dis[row] * (T(X)[row] @ W) ------------
// 128 rows / 512 threads per block; B staged once per 128 rows in LDS.
template<int SRC_F16, int TRANS>
__global__ __launch_bounds__(512) void gemm_mfma(const void* __restrict__ Xv,
                                                 const f16* __restrict__ Wt,
                                                 const float* __restrict__ stats,
                                                 const float* __restrict__ gamma,
                                                 const float* __restrict__ beta,
                                                 const float* __restrict__ dis,
                                                 f16* __restrict__ Y, int n) {
    __shared__ f16 Ah[128][136];
    __shared__ f16 Bh[128][136];
    __shared__ float sc[HC], sh[HC];
    const int tid  = threadIdx.x;
    const int row0 = blockIdx.x * 128;

    if constexpr (TRANS) {
        if (tid < 128) {
            float s = 0.f, q = 0.f;
#pragma unroll
            for (int t = 0; t < NSTRIPE; ++t) {
                s += stats[t * 256 + tid];
                q += stats[t * 256 + 128 + tid];
            }
            float m = s / (float)n;
            float v = q / (float)n - m * m;
            float scv = gamma[tid] * rsqrtf(fmaxf(v, 0.f) + EPS_BN);
            sc[tid] = scv;
            sh[tid] = beta[tid] - m * scv;
        }
    }

#pragma unroll
    for (int i = 0; i < 4; ++i) {
        int idx = i * 512 + tid;
        int r = idx >> 4, g = idx & 15;
        *(f16x8*)&Bh[r][g * 8] = *(const f16x8*)(Wt + (size_t)r * HC + g * 8);
    }
    __syncthreads();   // sc/sh + Bh visible

#pragma unroll
    for (int i = 0; i < 4; ++i) {
        int idx = i * 512 + tid;
        int r = idx >> 4, g = idx & 15;
        int grow = row0 + r;
        f16x8 h = {};
        if (grow < n) {
            if constexpr (SRC_F16) {
                f16x8 v = *(const f16x8*)((const f16*)Xv + (size_t)grow * HC + g * 8);
                if constexpr (TRANS) {
#pragma unroll
                    for (int j = 0; j < 8; ++j) {
                        float f = (float)v[j];
                        f = fmaxf(fmaf(f, sc[g * 8 + j], sh[g * 8 + j]), 0.f);
                        h[j] = (f16)f;
                    }
                } else h = v;
            } else {
                const float* X = (const float*)Xv;
                float4 a = *(const float4*)(X + (size_t)grow * HC + g * 8);
                float4 c = *(const float4*)(X + (size_t)grow * HC + g * 8 + 4);
                h[0] = (f16)a.x; h[1] = (f16)a.y; h[2] = (f16)a.z; h[3] = (f16)a.w;
                h[4] = (f16)c.x; h[5] = (f16)c.y; h[6] = (f16)c.z; h[7] = (f16)c.w;
            }
        }
        *(f16x8*)&Ah[r][g * 8] = h;
    }
    __syncthreads();

    const int wv   = tid >> 6;          // 0..7, wave handles rows wv*16..+15
    const int lane = tid & 63;
    const int m    = lane & 15;
    const int kq   = (lane >> 4) * 8;

    f32x4 acc[8] = {};
#pragma unroll
    for (int kc = 0; kc < HC; kc += 32) {
        f16x8 a = *(const f16x8*)&Ah[wv * 16 + m][kc + kq];
#pragma unroll
        for (int t = 0; t < 8; ++t) {
            f16x8 b = *(const f16x8*)&Bh[t * 16 + m][kc + kq];
            acc[t] = __builtin_amdgcn_mfma_f32_16x16x32_f16(a, b, acc[t], 0, 0, 0);
        }
    }

    // epilogue: scale by dis, transpose through Ah, vector-store
    __syncthreads();
    {
        const int rg = (lane >> 4) * 4;
        float dv[4];
#pragma unroll
        for (int r = 0; r < 4; ++r) {
            int grow = row0 + wv * 16 + rg + r;
            dv[r] = (grow < n) ? dis[grow] : 0.f;
        }
#pragma unroll
        for (int t = 0; t < 8; ++t)
#pragma unroll
            for (int r = 0; r < 4; ++r)
                Ah[wv * 16 + rg + r][t * 16 + m] = (f16)(acc[t][r] * dv[r]);
    }
    __syncthreads();
#pragma unroll
    for (int i = 0; i < 4; ++i) {
        int idx = i * 512 + tid;
        int r = idx >> 4, g = idx & 15;
        int grow = row0 + r;
        if (grow < n)
            *(f16x8*)(Y + (size_t)grow * HC + g * 8) = *(const f16x8*)&Ah[r][g * 8];
    }
}

// ---------------- CSR gather agg, 4 gathers in flight -----------------------
// xws[s] = dis[s]*xw[s]; out[v] = dis[v]*(sum_e xws[s] + xws[v]) + b.
__global__ __launch_bounds__(256) void gcn_agg_f16(const f16* __restrict__ xws,
                                                   const int* __restrict__ srcs,
                                                   const int2* __restrict__ rowptr2,
                                                   const float* __restrict__ dis,
                                                   const float* __restrict__ bias,
                                                   f16* __restrict__ out,
                                                   float* __restrict__ stats,
                                                   int n, int nwaves) {
    __shared__ float lds_s[4][128], lds_q[4][128];
    const int wv   = threadIdx.x >> 6;
    const int lane = threadIdx.x & 63;
    const int g    = lane >> 4;      // edge subgroup 0..3
    const int cg   = lane & 15;      // channel group (8 channels)

    float b8[8];
#pragma unroll
    for (int j = 0; j < 8; ++j) b8[j] = bias[cg * 8 + j];

    float s8[8] = {}, q8[8] = {};

    for (int node = blockIdx.x * 4 + wv; node < n; node += nwaves) {
        const int2 rp = rowptr2[node];
        const int e1 = rp.y;
        float acc[8] = {};
        int e  = rp.x;
        int i0 = e + g, i1 = i0 + 4, i2 = i0 + 8, i3 = i0 + 12;
        int s0 = (i0 < e1) ? srcs[i0] : n;   // n -> zero pad row
        int s1 = (i1 < e1) ? srcs[i1] : n;
        int s2 = (i2 < e1) ? srcs[i2] : n;
        int s3 = (i3 < e1) ? srcs[i3] : n;
        while (e < e1) {
            int en = e + 16;
            int j0 = en + g, j1 = j0 + 4, j2 = j0 + 8, j3 = j0 + 12;
            int t0 = (j0 < e1) ? srcs[j0] : n;   // prefetch next iter's indices
            int t1 = (j1 < e1) ? srcs[j1] : n;
            int t2 = (j2 < e1) ? srcs[j2] : n;
            int t3 = (j3 < e1) ? srcs[j3] : n;
            f16x8 v0 = *(const f16x8*)(xws + (size_t)s0 * HC + cg * 8);
            f16x8 v1 = *(const f16x8*)(xws + (size_t)s1 * HC + cg * 8);
            f16x8 v2 = *(const f16x8*)(xws + (size_t)s2 * HC + cg * 8);
            f16x8 v3 = *(const f16x8*)(xws + (size_t)s3 * HC + cg * 8);
            f16x8 p01 = v0 + v1;                 // v_pk_add_f16, zeros exact
            f16x8 p23 = v2 + v3;
#pragma unroll
            for (int j = 0; j < 8; ++j)
                acc[j] += (float)p01[j] + (float)p23[j];
            s0 = t0; s1 = t1; s2 = t2; s3 = t3; e = en;
        }
#pragma unroll
        for (int j = 0; j < 8; ++j) acc[j] += __shfl_xor(acc[j], 16);
#pragma unroll
        for (int j = 0; j < 8; ++j) acc[j] += __shfl_xor(acc[j], 32);

        if (g == 0) {
            float dv = dis[node];
            f16x8 self = *(const f16x8*)(xws + (size_t)node * HC + cg * 8);
            f16x8 o;
#pragma unroll
            for (int j = 0; j < 8; ++j) {
                float r = fmaf(acc[j] + (float)self[j], dv, b8[j]);
                o[j] = (f16)r;
                s8[j] += r;
                q8[j] += r * r;
            }
            *(f16x8*)(out + (size_t)node * HC + cg * 8) = o;
        }
    }

    if (g == 0) {
#pragma unroll
        for (int j = 0; j < 8; ++j) {
            lds_s[wv][cg * 8 + j] = s8[j];
            lds_q[wv][cg * 8 + j] = q8[j];
        }
    }
    __syncthreads();
    float* stripe = stats + (size_t)(blockIdx.x & (NSTRIPE - 1)) * 256;
    if (threadIdx.x < 128) {
        float s = lds_s[0][threadIdx.x] + lds_s[1][threadIdx.x] +
                  lds_s[2][threadIdx.x] + lds_s[3][threadIdx.x];
        float q = lds_q[0][threadIdx.x] + lds_q[1][threadIdx.x] +
                  lds_q[2][threadIdx.x] + lds_q[3][threadIdx.x];
        atomicAdd(&stripe[threadIdx.x], s);
        atomicAdd(&stripe[128 + threadIdx.x], q);
    }
}

// ---------------- MFMA MLP head (BN2 finalize + BN+ReLU + both layers) ------
__global__ __launch_bounds__(256) void mlp_mfma(const f16* __restrict__ h,
                                                const float* __restrict__ stats,
                                                const float* __restrict__ gamma,
                                                const float* __restrict__ beta,
                                                const f16* __restrict__ Wm1t,
                                                const float* __restrict__ bm1,
                                                const float* __restrict__ Wm2,
                                                const float* __restrict__ bm2,
                                                float* __restrict__ out, int n) {
    __shared__ f16 Hs[64][136];
    __shared__ f16 Ws[64][136];
    __shared__ float sc[HC], sh[HC], bmv[64], w2v[64];
    const int tid  = threadIdx.x;
    const int row0 = blockIdx.x * 64;

    if (tid < 128) {
        float s = 0.f, q = 0.f;
#pragma unroll
        for (int t = 0; t < NSTRIPE; ++t) {
            s += stats[t * 256 + tid];
            q += stats[t * 256 + 128 + tid];
        }
        float m = s / (float)n;
        float v = q / (float)n - m * m;
        float scv = gamma[tid] * rsqrtf(fmaxf(v, 0.f) + EPS_BN);
        sc[tid] = scv;
        sh[tid] = beta[tid] - m * scv;
    }
    if (tid < 64) { bmv[tid] = bm1[tid]; w2v[tid] = Wm2[tid]; }

#pragma unroll
    for (int i = 0; i < 4; ++i) {
        int idx = i * 256 + tid;
        int r = idx >> 4, g = idx & 15;
        *(f16x8*)&Ws[r][g * 8] = *(const f16x8*)(Wm1t + (size_t)r * HC + g * 8);
    }
    __syncthreads();

#pragma unroll
    for (int i = 0; i < 4; ++i) {
        int idx = i * 256 + tid;
        int r = idx >> 4, g = idx & 15;
        int grow = row0 + r;
        f16x8 hv = {};
        if (grow < n) {
            f16x8 v = *(const f16x8*)(h + (size_t)grow * HC + g * 8);
#pragma unroll
            for (int j = 0; j < 8; ++j) {
                float f = (float)v[j];
                f = fmaxf(fmaf(f, sc[g * 8 + j], sh[g * 8 + j]), 0.f);
                hv[j] = (f16)f;
            }
        }
        *(f16x8*)&Hs[r][g * 8] = hv;
    }
    __syncthreads();

    const int wv   = tid >> 6;
    const int lane = tid & 63;
    const int m    = lane & 15;
    const int kq   = (lane >> 4) * 8;

    f32x4 acc[4] = {};
#pragma unroll
    for (int kc = 0; kc < HC; kc += 32) {
        f16x8 a = *(const f16x8*)&Hs[wv * 16 + m][kc + kq];
#pragma unroll
        for (int t = 0; t < 4; ++t) {
            f16x8 b = *(const f16x8*)&Ws[t * 16 + m][kc + kq];
            acc[t] = __builtin_amdgcn_mfma_f32_16x16x32_f16(a, b, acc[t], 0, 0, 0);
        }
    }

    float part[4];
#pragma unroll
    for (int reg = 0; reg < 4; ++reg) {
        float s = 0.f;
#pragma unroll
        for (int t = 0; t < 4; ++t) {
            int col = t * 16 + m;
            s += fmaxf(acc[t][reg] + bmv[col], 0.f) * w2v[col];
        }
        part[reg] = s;
    }
#pragma unroll
    for (int off = 1; off < 16; off <<= 1) {
#pragma unroll
        for (int reg = 0; reg < 4; ++reg)
            part[reg] += __shfl_xor(part[reg], off);
    }
    if (m == 0) {
        int rbase = row0 + wv * 16 + (lane >> 4) * 4;
        float bb = bm2[0];
#pragma unroll
        for (int reg = 0; reg < 4; ++reg) {
            int row = rbase + reg;
            if (row < n) out[row] = part[reg] + bb;
        }
    }
}

extern "C" void kernel_launch(void* const* d_in, const int* in_sizes, int n_in,
                              void* d_out, int out_size, void* d_ws, size_t ws_size,
                              hipStream_t stream) {
    const float* x   = (const float*)d_in[0];
    const int*   ei  = (const int*)  d_in[1];
    const float* W1  = (const float*)d_in[2];
    const float* b1  = (const float*)d_in[3];
    const float* g1  = (const float*)d_in[4];
    const float* be1 = (const float*)d_in[5];
    const float* W2  = (const float*)d_in[6];
    const float* b2  = (const float*)d_in[7];
    const float* g2  = (const float*)d_in[8];
    const float* be2 = (const float*)d_in[9];
    const float* Wm1 = (const float*)d_in[10];
    const float* bm1 = (const float*)d_in[11];
    const float* Wm2 = (const float*)d_in[12];
    const float* bm2 = (const float*)d_in[13];
    float* out = (float*)d_out;

    const int n = in_sizes[0] / HC;       // 100000
    const int E = in_sizes[1] / 2;        // 1600000
    const int* srcp = ei;
    const int* dstp = ei + E;
    const int nb = (n + BNODES - 1) >> BSHIFT;   // 391 buckets

    char* ws = (char*)d_ws;
    size_t off = 0;
    auto alloc = [&](size_t bytes) { void* p = ws + off; off = (off + bytes + 511) & ~511ULL; return p; };
    // xws FIRST so that {pad row | gcur | stats} is one contiguous zero range
    f16*    xws     = (f16*)   alloc((size_t)(n + 1) * HC * 2);   // +1 zero pad row
    int*    gcur    = (int*)   alloc(NBKT * 4);
    float*  stats   = (float*) alloc(2 * NSTRIPE * 256 * 4);      // stats1 | stats2
    float*  stats1  = stats;
    float*  stats2  = stats + NSTRIPE * 256;
    float*  dis     = (float*) alloc((size_t)n * 4);
    int2*   rowptr2 = (int2*)  alloc((size_t)n * 8);
    unsigned int* packed = (unsigned int*)alloc((size_t)nb * BCAP * 4);
    int*    srcs    = (int*)   alloc((size_t)nb * BCAP * 4);
    f16*    bufBh   = (f16*)   alloc((size_t)n * HC * 2);
    f16*    Wt1     = (f16*)   alloc((size_t)HC * HC * 2);
    f16*    Wt2     = (f16*)   alloc((size_t)HC * HC * 2);
    f16*    Wm1t    = (f16*)   alloc((size_t)64 * HC * 2);

    const int gemmBlocks = (n + 127) / 128;       // 128-row blocks, 512 threads
    const int mlpBlocks  = (n + 63) / 64;
    const int binBlocks  = (E + CHUNK - 1) / CHUNK;   // 391
    const int wprepBlks  = 40;                    // 40960 / 1024
    const int aggWaves   = AGG_BLOCKS * 4;

    // ---- single memset: pad row + (alignment slack) + gcur + stats ----
    {
        char* z0 = (char*)(xws + (size_t)n * HC);
        size_t zlen = (size_t)((char*)(stats + 2 * NSTRIPE * 256) - z0);
        hipMemsetAsync(z0, 0, zlen, stream);
    }

    // ---- CSR build: bin -> per-bucket sort (+ weight prep riding along) ----
    edge_bin<<<binBlocks, 1024, 0, stream>>>(srcp, dstp, gcur, packed, E);
    sort_wprep<<<nb + wprepBlks, 1024, 0, stream>>>(packed, gcur, rowptr2, dis, srcs, n, nb,
                                                    W1, W2, Wm1, Wt1, Wt2, Wm1t);

    // ---- layer 1 ----
    gemm_mfma<0, 0><<<gemmBlocks, 512, 0, stream>>>(x, Wt1, nullptr, nullptr, nullptr,
                                                    dis, xws, n);
    gcn_agg_f16<<<AGG_BLOCKS, 256, 0, stream>>>(xws, srcs, rowptr2, dis, b1,
                                                bufBh, stats1, n, aggWaves);

    // ---- layer 2 (BN1 finalize + BN+ReLU fused into GEMM staging) ----
    gemm_mfma<1, 1><<<gemmBlocks, 512, 0, stream>>>(bufBh, Wt2, stats1, g1, be1,
                                                    dis, xws, n);
    gcn_agg_f16<<<AGG_BLOCKS, 256, 0, stream>>>(xws, srcs, rowptr2, dis, b2,
                                                bufBh, stats2, n, aggWaves);

    // ---- MLP head (BN2 finalize + BN+ReLU + both layers fused, MFMA) ----
    mlp_mfma<<<mlpBlocks, 256, 0, stream>>>(bufBh, stats2, g2, be2, Wm1t, bm1, Wm2, bm2,
                                            out, n);
}